// Round 7
// baseline (1135.193 us; speedup 1.0000x reference)
//
#include <hip/hip_runtime.h>

typedef unsigned short u16;
typedef unsigned int   u32;
typedef unsigned long long u64;

constexpr int NROW  = 16384;   // B*T
constexpr int DIM   = 512;
constexpr int KCODE = 8192;

// MFMA argmin tiling (256^2 main kernel; 128^2 constants kept for fallback)
constexpr int BM   = 128;
constexpr int BN   = 128;
constexpr int BK   = 32;
constexpr int LSTR = 36;

// d_out offsets (in floats)
constexpr size_t Q_OFF = 0;          // quantized_st [16,1024,512]
constexpr size_t T_OFF = 8388608;    // targets [16,1024]
constexpr size_t L_OFF = 8404992;    // extra_losses scalar
constexpr size_t E_OFF = 8404993;    // new_embeddings [8192,512]
constexpr size_t C_OFF = 12599297;   // new_cs [8192]
constexpr size_t W_OFF = 12607489;   // new_w [8192,512]

// ws offsets (bytes)
constexpr size_t WS_KEYS   = 0;        // u64[NROW]
constexpr size_t WS_CSIZE  = 131072;   // float[KCODE]
constexpr size_t WS_COMMIT = 163840;   // float
constexpr size_t WS_CSSUM  = 163844;   // float
constexpr size_t WS_XNORM  = 196608;   // float[NROW]
constexpr size_t WS_ENORM  = 262144;   // float[KCODE]
constexpr size_t WS_ESUM   = 327680;   // float[KCODE*DIM]
constexpr size_t WS_NEEDED = WS_ESUM + (size_t)KCODE * DIM * 4;   // 17,104,896
// pre-split bf16 hi/lo planes (row-major [N][512] u16)
constexpr size_t WS_FH = WS_NEEDED;
constexpr size_t WS_FL = WS_FH + (size_t)NROW * DIM * 2;
constexpr size_t WS_EH = WS_FL + (size_t)NROW * DIM * 2;
constexpr size_t WS_EL = WS_EH + (size_t)KCODE * DIM * 2;
constexpr size_t WS_BIG = WS_EL + (size_t)KCODE * DIM * 2;         // ~67.4 MB

// ---------------- kernel 1: row sum-of-squares, numpy pairwise order --------
__global__ void rownorm_kernel(const float* __restrict__ src, float* __restrict__ dst) {
    #pragma clang fp contract(off)
    __shared__ float s[4][DIM];
    __shared__ float rr[4][32];
    const int wave = threadIdx.x >> 6, lane = threadIdx.x & 63;
    const int row = blockIdx.x * 4 + wave;
    const float4* p = (const float4*)(src + (size_t)row * DIM);
    float4 v0 = p[lane];
    float4 v1 = p[lane + 64];
    *(float4*)&s[wave][lane * 4] = v0;
    *(float4*)&s[wave][(lane + 64) * 4] = v1;
    __syncthreads();
    if (lane < 32) {
        const int b = lane >> 3, j = lane & 7;
        const float* q = &s[wave][b * 128 + j];
        float x = q[0];
        float r = x * x;
        for (int t = 1; t < 16; ++t) {
            float y = q[8 * t];
            float py = y * y;
            r = r + py;
        }
        rr[wave][lane] = r;
    }
    __syncthreads();
    if (lane == 0) {
        const float* R = rr[wave];
        float B0 = ((R[0] + R[1]) + (R[2] + R[3])) + ((R[4] + R[5]) + (R[6] + R[7]));
        float B1 = ((R[8] + R[9]) + (R[10] + R[11])) + ((R[12] + R[13]) + (R[14] + R[15]));
        float B2 = ((R[16] + R[17]) + (R[18] + R[19])) + ((R[20] + R[21]) + (R[22] + R[23]));
        float B3 = ((R[24] + R[25]) + (R[26] + R[27])) + ((R[28] + R[29]) + (R[30] + R[31]));
        dst[row] = (B0 + B1) + (B2 + B3);
    }
}

// ---------------- helpers ---------------------------------------------------
typedef short bf16x8 __attribute__((ext_vector_type(8)));
typedef float f32x16 __attribute__((ext_vector_type(16)));

__device__ __forceinline__ bf16x8 frag_of(int4 t) {
    return __builtin_bit_cast(bf16x8, t);
}

// fp32 -> bf16 round-to-nearest-even (non-NaN inputs), as u32 in low 16 bits
__device__ __forceinline__ u32 bf16rne(float x) {
    u32 u = __float_as_uint(x);
    return (u + 0x7fffu + ((u >> 16) & 1u)) >> 16;
}

// fp32x4 -> bf16 hi (RNE) + bf16 lo (RNE of residual); packed pairs
__device__ __forceinline__ void split4(float4 v, u32& hp0, u32& hp1, u32& lp0, u32& lp1) {
    u32 h0 = bf16rne(v.x), h1 = bf16rne(v.y), h2 = bf16rne(v.z), h3 = bf16rne(v.w);
    hp0 = h0 | (h1 << 16);
    hp1 = h2 | (h3 << 16);
    float r0 = v.x - __uint_as_float(h0 << 16);
    float r1 = v.y - __uint_as_float(h1 << 16);
    float r2 = v.z - __uint_as_float(h2 << 16);
    float r3 = v.w - __uint_as_float(h3 << 16);
    lp0 = bf16rne(r0) | (bf16rne(r1) << 16);
    lp1 = bf16rne(r2) | (bf16rne(r3) << 16);
}

__device__ __forceinline__ u64 packkey(float v, int code) {
    u32 vb = __float_as_uint(v);
    vb = (vb & 0x80000000u) ? ~vb : (vb | 0x80000000u);
    return ((u64)vb << 32) | (u32)code;
}

// async global -> LDS, 16 B per lane; LDS dest = wave-uniform base + lane*16
typedef __attribute__((address_space(1))) const void* gas_ptr;
typedef __attribute__((address_space(3))) void*       las_ptr;
__device__ __forceinline__ void gload16(const void* g, void* l) {
    __builtin_amdgcn_global_load_lds((gas_ptr)(unsigned long long)g,
                                     (las_ptr)(unsigned)(unsigned long long)l,
                                     16, 0, 0);
}

// ---------------- kernel 1b: pre-split fp32 -> bf16 hi/lo -------------------
__global__ void split_kernel(const float* __restrict__ src,
                             u16* __restrict__ hi, u16* __restrict__ lo) {
    const size_t i = (size_t)blockIdx.x * 256 + threadIdx.x;   // 8 floats per thread
    const float4* p = (const float4*)src;
    float4 a = p[i * 2], b = p[i * 2 + 1];
    u32 ah0, ah1, al0, al1, bh0, bh1, bl0, bl1;
    split4(a, ah0, ah1, al0, al1);
    split4(b, bh0, bh1, bl0, bl1);
    ((uint4*)hi)[i] = make_uint4(ah0, ah1, bh0, bh1);
    ((uint4*)lo)[i] = make_uint4(al0, al1, bl0, bl1);
}

// ---------------- kernel 2: argmin via pre-split bf16 MFMA, 256^2 tile ------
// 512 thr = 8 waves (2 row x 4 col), per-wave output 128x64, acc[4][2] f32x16.
// LDS per buffer: 4 planes (Ah,Al,Bh,Bl) x 1024 slots x 16 B = 64 KB.
// Plane slot s <-> rb_g = s>>7, k8 = (s>>5)&3, c5 = s&31; row_local = rb_g*32+c5,
// global int4 idx = (base+row_local)*64 + kt*4 + k8.
// Staging: 64 gloads/block-tile; wave wv, h=0..7 -> g = wv*8+h, plane g>>4,
// group gg = g&15, lds slot gg*64+lane (== linear formula above).
// Protocol: 2-deep prefetch, counted vmcnt(8), raw barriers (round-6-proven).
__attribute__((amdgpu_waves_per_eu(2, 2)))
__launch_bounds__(512)
__global__ void argmin_ps_kernel(const u16* __restrict__ fH, const u16* __restrict__ fL,
                                 const u16* __restrict__ eH, const u16* __restrict__ eL,
                                 const float* __restrict__ xnorm,
                                 const float* __restrict__ enorm,
                                 u64* __restrict__ keys) {
    __shared__ int4 sP[2][4][1024];        // 128 KB
    __shared__ float sXn[256], sEn[256];

    const int tid = threadIdx.x;
    // XCD-bijective swizzle: 2048 % 8 == 0; cp varies fastest inside an XCD
    const int swz = ((int)blockIdx.x & 7) * 256 + ((int)blockIdx.x >> 3);
    const int cp = swz & 31;               // 32 code panels
    const int rp = swz >> 5;               // 64 row panels
    const int row0 = rp * 256;
    const int code0 = cp * 256;

    if (tid < 256) sXn[tid] = xnorm[row0 + tid];
    else           sEn[tid - 256] = enorm[code0 + (tid - 256)];

    const int lane = tid & 63;
    const int wv = tid >> 6;
    const int wr = wv >> 2, wc = wv & 3;   // 2x4 waves over 128x64 sub-tiles
    const int c5 = lane & 31, hgrp = lane >> 5;

    const int4* fH4 = (const int4*)fH;
    const int4* fL4 = (const int4*)fL;
    const int4* eH4 = (const int4*)eH;
    const int4* eL4 = (const int4*)eL;

    // per-lane staging pointers + LDS plane/slot bases for the 8 slot-groups
    const int4* gp[8];
    int gpl[8], gsb[8];
    #pragma unroll
    for (int h = 0; h < 8; ++h) {
        const int g = wv * 8 + h;          // 0..63
        const int p = g >> 4;              // plane 0..3
        const int gg = g & 15;             // group within plane
        const int row_local = (gg >> 1) * 32 + c5;
        const int k8b = (gg & 1) * 2 + hgrp;
        const int base = (p < 2) ? row0 : code0;
        const int4* src = (p == 0) ? fH4 : (p == 1) ? fL4 : (p == 2) ? eH4 : eL4;
        gp[h] = src + (size_t)(base + row_local) * 64 + k8b;
        gpl[h] = p;
        gsb[h] = gg * 64 + lane;
    }

    f32x16 acc[4][2] = {};

    auto STAGE = [&](int buf, int kt) {    // 8 VMEM instructions / wave
        #pragma unroll
        for (int h = 0; h < 8; ++h)
            gload16(gp[h] + kt * 4, (void*)&sP[buf][gpl[h]][gsb[h]]);
    };
    auto COMPUTE = [&](int buf) {
        // MFMA: 3-pass split-bf16 (xh*eh + xh*el + xl*eh), same per-acc order
        #pragma unroll
        for (int s = 0; s < 2; ++s) {
            const int k8 = s * 2 + hgrp;
            bf16x8 bh[2], bl[2];
            #pragma unroll
            for (int cb = 0; cb < 2; ++cb) {
                bh[cb] = frag_of(sP[buf][2][(wc * 2 + cb) * 128 + k8 * 32 + c5]);
                bl[cb] = frag_of(sP[buf][3][(wc * 2 + cb) * 128 + k8 * 32 + c5]);
            }
            #pragma unroll
            for (int rb = 0; rb < 4; ++rb) {
                bf16x8 ah = frag_of(sP[buf][0][(wr * 4 + rb) * 128 + k8 * 32 + c5]);
                bf16x8 al = frag_of(sP[buf][1][(wr * 4 + rb) * 128 + k8 * 32 + c5]);
                #pragma unroll
                for (int cb = 0; cb < 2; ++cb) {
                    acc[rb][cb] = __builtin_amdgcn_mfma_f32_32x32x16_bf16(ah, bh[cb], acc[rb][cb], 0, 0, 0);
                    acc[rb][cb] = __builtin_amdgcn_mfma_f32_32x32x16_bf16(ah, bl[cb], acc[rb][cb], 0, 0, 0);
                    acc[rb][cb] = __builtin_amdgcn_mfma_f32_32x32x16_bf16(al, bh[cb], acc[rb][cb], 0, 0, 0);
                }
            }
        }
    };

    // prologue: stage tiles 0 and 1 (16 VMEM in flight per wave)
    STAGE(0, 0);
    STAGE(1, 1);

    int cur = 0;
    #pragma unroll 1
    for (int kt = 0; kt < DIM / BK; ++kt) {
        // wait for tile kt only (oldest 8); tile kt+1's 8 stay in flight
        if (kt < DIM / BK - 1) {
            asm volatile("s_waitcnt vmcnt(8)" ::: "memory");
        } else {
            asm volatile("s_waitcnt vmcnt(0)" ::: "memory");
        }
        __builtin_amdgcn_s_barrier();      // tile kt visible block-wide
        asm volatile("" ::: "memory");     // pin ds_reads below the barrier
        COMPUTE(cur);
        __builtin_amdgcn_s_barrier();      // all waves done reading buf cur
        if (kt + 2 < DIM / BK) STAGE(cur, kt + 2);
        cur ^= 1;
    }

    // epilogue: d2 = (xn - 2*dot) + en, per-row argmin, atomicMin key protocol
    #pragma unroll
    for (int rb = 0; rb < 4; ++rb) {
        #pragma unroll
        for (int r = 0; r < 16; ++r) {
            const int rowt = wr * 128 + rb * 32 + (r & 3) + 8 * (r >> 2) + 4 * hgrp;
            const float xv = sXn[rowt];
            const int ct0 = wc * 64 + c5;
            float v0 = fmaf(-2.0f, acc[rb][0][r], xv) + sEn[ct0];
            float v1 = fmaf(-2.0f, acc[rb][1][r], xv) + sEn[ct0 + 32];
            u64 ka = packkey(v0, code0 + ct0);
            u64 kb = packkey(v1, code0 + ct0 + 32);
            u64 key = (kb < ka) ? kb : ka;
            #pragma unroll
            for (int m = 1; m < 32; m <<= 1) {
                u64 o = __shfl_xor(key, m, 64);
                if (o < key) key = o;
            }
            if (c5 == 0) atomicMin(&keys[row0 + rowt], key);
        }
    }
}

// ---------------- kernel 2-fallback: in-loop-convert argmin (round-2) -------
__launch_bounds__(256, 3)
__global__ void argmin_conv_kernel(const float* __restrict__ feat,
                                   const float* __restrict__ emb,
                                   const float* __restrict__ xnorm,
                                   const float* __restrict__ enorm,
                                   u64* __restrict__ keys) {
    __shared__ u16 sAh[BM][LSTR], sAl[BM][LSTR], sBh[BN][LSTR], sBl[BN][LSTR];
    __shared__ float sXn[BM], sEn[BN];

    const int tid = threadIdx.x;
    const int swz = ((int)blockIdx.x & 7) * 1024 + ((int)blockIdx.x >> 3);
    const int cp = swz & 63;
    const int rp = swz >> 6;
    const int row0 = rp * BM;
    const int code0 = cp * BN;

    if (tid < BM) sXn[tid] = xnorm[row0 + tid];
    else          sEn[tid - BM] = enorm[code0 + (tid - BM)];

    const int srow = tid >> 3;
    const int scol = (tid & 7) * 4;
    const float* aBase = feat + (size_t)row0 * DIM;
    const float* bBase = emb + (size_t)code0 * DIM;

    float4 pa[4], pb[4];
    #pragma unroll
    for (int l = 0; l < 4; ++l) {
        pa[l] = *(const float4*)&aBase[(size_t)(srow + 32 * l) * DIM + scol];
        pb[l] = *(const float4*)&bBase[(size_t)(srow + 32 * l) * DIM + scol];
    }

    const int lane = tid & 63;
    const int wv = tid >> 6;
    const int wr = wv & 1, wc = wv >> 1;
    const int c5 = lane & 31, hgrp = lane >> 5;

    f32x16 acc[2][2] = {};

    #pragma unroll 1
    for (int kt = 0; kt < DIM / BK; ++kt) {
        __syncthreads();
        #pragma unroll
        for (int l = 0; l < 4; ++l) {
            u32 h0, h1, q0, q1;
            split4(pa[l], h0, h1, q0, q1);
            *(uint2*)&sAh[srow + 32 * l][scol] = make_uint2(h0, h1);
            *(uint2*)&sAl[srow + 32 * l][scol] = make_uint2(q0, q1);
            split4(pb[l], h0, h1, q0, q1);
            *(uint2*)&sBh[srow + 32 * l][scol] = make_uint2(h0, h1);
            *(uint2*)&sBl[srow + 32 * l][scol] = make_uint2(q0, q1);
        }
        __syncthreads();
        if (kt + 1 < DIM / BK) {
            const int k0 = (kt + 1) * BK;
            #pragma unroll
            for (int l = 0; l < 4; ++l) {
                pa[l] = *(const float4*)&aBase[(size_t)(srow + 32 * l) * DIM + k0 + scol];
                pb[l] = *(const float4*)&bBase[(size_t)(srow + 32 * l) * DIM + k0 + scol];
            }
        }
        #pragma unroll
        for (int s = 0; s < 2; ++s) {
            const int kk = s * 16 + hgrp * 8;
            bf16x8 ah[2], al[2], bh[2], bl[2];
            #pragma unroll
            for (int i = 0; i < 2; ++i) {
                uint2 a0 = *(const uint2*)&sAh[64 * wr + 32 * i + c5][kk];
                uint2 a1 = *(const uint2*)&sAh[64 * wr + 32 * i + c5][kk + 4];
                ah[i] = frag_of(make_int4(a0.x, a0.y, a1.x, a1.y));
                uint2 c0 = *(const uint2*)&sAl[64 * wr + 32 * i + c5][kk];
                uint2 c1 = *(const uint2*)&sAl[64 * wr + 32 * i + c5][kk + 4];
                al[i] = frag_of(make_int4(c0.x, c0.y, c1.x, c1.y));
                uint2 b0 = *(const uint2*)&sBh[64 * wc + 32 * i + c5][kk];
                uint2 b1 = *(const uint2*)&sBh[64 * wc + 32 * i + c5][kk + 4];
                bh[i] = frag_of(make_int4(b0.x, b0.y, b1.x, b1.y));
                uint2 d0 = *(const uint2*)&sBl[64 * wc + 32 * i + c5][kk];
                uint2 d1 = *(const uint2*)&sBl[64 * wc + 32 * i + c5][kk + 4];
                bl[i] = frag_of(make_int4(d0.x, d0.y, d1.x, d1.y));
            }
            #pragma unroll
            for (int i = 0; i < 2; ++i) {
                #pragma unroll
                for (int j = 0; j < 2; ++j) {
                    acc[i][j] = __builtin_amdgcn_mfma_f32_32x32x16_bf16(ah[i], bh[j], acc[i][j], 0, 0, 0);
                    acc[i][j] = __builtin_amdgcn_mfma_f32_32x32x16_bf16(ah[i], bl[j], acc[i][j], 0, 0, 0);
                    acc[i][j] = __builtin_amdgcn_mfma_f32_32x32x16_bf16(al[i], bh[j], acc[i][j], 0, 0, 0);
                }
            }
        }
    }

    #pragma unroll
    for (int i = 0; i < 2; ++i) {
        #pragma unroll
        for (int r = 0; r < 16; ++r) {
            const int rowt = 64 * wr + 32 * i + (r & 3) + 8 * (r >> 2) + 4 * hgrp;
            const float xv = sXn[rowt];
            const int ct0 = 64 * wc + c5;
            float v0 = fmaf(-2.0f, acc[i][0][r], xv) + sEn[ct0];
            float v1 = fmaf(-2.0f, acc[i][1][r], xv) + sEn[ct0 + 32];
            u64 ka = packkey(v0, code0 + ct0);
            u64 kb = packkey(v1, code0 + ct0 + 32);
            u64 key = (kb < ka) ? kb : ka;
            #pragma unroll
            for (int m = 1; m < 32; m <<= 1) {
                u64 o = __shfl_xor(key, m, 64);
                if (o < key) key = o;
            }
            if (c5 == 0) atomicMin(&keys[row0 + rowt], key);
        }
    }
}

// ---------------- kernel 3: gather + commitment + scatter-add ---------------
__global__ void gather_kernel(const float* __restrict__ feat,
                              const float* __restrict__ emb,
                              const unsigned long long* __restrict__ keys,
                              float* __restrict__ qout,
                              float* __restrict__ targets,
                              float* __restrict__ esum,
                              float* __restrict__ csize,
                              float* __restrict__ commit) {
    const int row = blockIdx.x;
    const int code = (int)(keys[row] & 0x7fffffffu);
    const int d = threadIdx.x * 2;
    float2 f = *(const float2*)&feat[(size_t)row * DIM + d];
    float2 q = *(const float2*)&emb[(size_t)code * DIM + d];
    float2 qst;
    qst.x = f.x + (q.x - f.x);
    qst.y = f.y + (q.y - f.y);
    *(float2*)&qout[(size_t)row * DIM + d] = qst;
    float dx = f.x - qst.x, dy = f.y - qst.y;
    float local = dx * dx + dy * dy;
    #pragma unroll
    for (int off = 32; off; off >>= 1) local += __shfl_down(local, off, 64);
    __shared__ float wsum[4];
    int lane = threadIdx.x & 63, wv = threadIdx.x >> 6;
    if (lane == 0) wsum[wv] = local;
    __syncthreads();
    if (threadIdx.x == 0) {
        atomicAdd(commit, wsum[0] + wsum[1] + wsum[2] + wsum[3]);
        atomicAdd(&csize[code], 1.0f);
        targets[row] = (float)code;
    }
    atomicAdd(&esum[(size_t)code * DIM + d], f.x);
    atomicAdd(&esum[(size_t)code * DIM + d + 1], f.y);
}

// ---------------- kernel 4: new_cs + sum(new_cs) + loss ---------------------
__global__ void newcs_kernel(const float* __restrict__ ema_cs,
                             const float* __restrict__ csize,
                             float* __restrict__ out_cs,
                             float* __restrict__ cs_sum,
                             const float* __restrict__ commit,
                             float* __restrict__ out_loss) {
    int i = blockIdx.x * 256 + threadIdx.x;
    float v = 0.99f * ema_cs[i] + 0.01f * csize[i];
    out_cs[i] = v;
    float s = v;
    #pragma unroll
    for (int off = 32; off; off >>= 1) s += __shfl_down(s, off, 64);
    __shared__ float wsum[4];
    int lane = threadIdx.x & 63, wv = threadIdx.x >> 6;
    if (lane == 0) wsum[wv] = s;
    __syncthreads();
    if (threadIdx.x == 0)
        atomicAdd(cs_sum, wsum[0] + wsum[1] + wsum[2] + wsum[3]);
    if (blockIdx.x == 0 && threadIdx.x == 0)
        out_loss[0] = 0.25f * commit[0] / 8388608.0f;
}

// ---------------- kernel 5: new_w + new_embeddings --------------------------
__global__ void final_kernel(const float* __restrict__ ema_w,
                             const float* __restrict__ esum,
                             const float* __restrict__ new_cs,
                             const float* __restrict__ cs_sum,
                             float* __restrict__ out_w,
                             float* __restrict__ out_emb) {
    size_t i4 = ((size_t)blockIdx.x * 256 + threadIdx.x) * 4;
    int k = (int)(i4 >> 9);
    float S = cs_sum[0] + (float)KCODE * 1e-5f;
    float4 es = *(const float4*)&esum[i4];
    float4 ew = *(const float4*)&ema_w[i4];
    float w0 = 0.99f * ew.x + 0.01f * es.x;
    float w1 = 0.99f * ew.y + 0.01f * es.y;
    float w2 = 0.99f * ew.z + 0.01f * es.z;
    float w3 = 0.99f * ew.w + 0.01f * es.w;
    out_w[i4 + 0] = w0; out_w[i4 + 1] = w1; out_w[i4 + 2] = w2; out_w[i4 + 3] = w3;
    float scale = S / (new_cs[k] + 1e-5f);
    out_emb[i4 + 0] = w0 * scale; out_emb[i4 + 1] = w1 * scale;
    out_emb[i4 + 2] = w2 * scale; out_emb[i4 + 3] = w3 * scale;
}

// ---------------------------------------------------------------------------
extern "C" void kernel_launch(void* const* d_in, const int* in_sizes, int n_in,
                              void* d_out, int out_size, void* d_ws, size_t ws_size,
                              hipStream_t stream) {
    const float* feat   = (const float*)d_in[0];
    const float* emb    = (const float*)d_in[1];
    const float* ema_cs = (const float*)d_in[2];
    const float* ema_w  = (const float*)d_in[3];
    float* out = (float*)d_out;
    char* ws = (char*)d_ws;
    if (ws_size < WS_NEEDED) return;

    u64* keys     = (u64*)(ws + WS_KEYS);
    float* csize  = (float*)(ws + WS_CSIZE);
    float* commit = (float*)(ws + WS_COMMIT);
    float* cssum  = (float*)(ws + WS_CSSUM);
    float* xnorm  = (float*)(ws + WS_XNORM);
    float* enorm  = (float*)(ws + WS_ENORM);
    float* esum   = (float*)(ws + WS_ESUM);

    (void)hipMemsetAsync(ws + WS_KEYS, 0xFF, (size_t)NROW * 8, stream);
    (void)hipMemsetAsync(ws + WS_CSIZE, 0, WS_CSSUM + 4 - WS_CSIZE, stream);
    (void)hipMemsetAsync(ws + WS_ESUM, 0, (size_t)KCODE * DIM * 4, stream);

    rownorm_kernel<<<NROW / 4, 256, 0, stream>>>(feat, xnorm);
    rownorm_kernel<<<KCODE / 4, 256, 0, stream>>>(emb, enorm);

    if (ws_size >= WS_BIG) {
        u16* fH = (u16*)(ws + WS_FH);
        u16* fL = (u16*)(ws + WS_FL);
        u16* eH = (u16*)(ws + WS_EH);
        u16* eL = (u16*)(ws + WS_EL);
        split_kernel<<<(NROW * DIM) / (256 * 8), 256, 0, stream>>>(feat, fH, fL);
        split_kernel<<<(KCODE * DIM) / (256 * 8), 256, 0, stream>>>(emb, eH, eL);
        argmin_ps_kernel<<<(NROW / 256) * (KCODE / 256), 512, 0, stream>>>(fH, fL, eH, eL,
                                                                           xnorm, enorm, keys);
    } else {
        argmin_conv_kernel<<<(NROW / BM) * (KCODE / BN), 256, 0, stream>>>(feat, emb,
                                                                           xnorm, enorm, keys);
    }

    gather_kernel<<<NROW, 256, 0, stream>>>(feat, emb, keys, out + Q_OFF, out + T_OFF,
                                            esum, csize, commit);
    newcs_kernel<<<KCODE / 256, 256, 0, stream>>>(ema_cs, csize, out + C_OFF, cssum, commit, out + L_OFF);
    final_kernel<<<KCODE * DIM / 1024, 256, 0, stream>>>(ema_w, esum, out + C_OFF, cssum,
                                                         out + W_OFF, out + E_OFF);
}

// Round 8
// 1031.422 us; speedup vs baseline: 1.1006x; 1.1006x over previous
//
#include <hip/hip_runtime.h>

typedef unsigned short u16;
typedef unsigned int   u32;
typedef unsigned long long u64;

constexpr int NROW  = 16384;   // B*T
constexpr int DIM   = 512;
constexpr int KCODE = 8192;

// MFMA argmin tiling
constexpr int BM   = 128;   // rows per block
constexpr int BN   = 128;   // codes per block
constexpr int BK   = 32;    // depth chunk
constexpr int LSTR = 36;    // LDS row stride for fallback kernel

// d_out offsets (in floats)
constexpr size_t Q_OFF = 0;          // quantized_st [16,1024,512]
constexpr size_t T_OFF = 8388608;    // targets [16,1024]
constexpr size_t L_OFF = 8404992;    // extra_losses scalar
constexpr size_t E_OFF = 8404993;    // new_embeddings [8192,512]
constexpr size_t C_OFF = 12599297;   // new_cs [8192]
constexpr size_t W_OFF = 12607489;   // new_w [8192,512]

// ws offsets (bytes)
constexpr size_t WS_KEYS   = 0;        // u64[NROW]
constexpr size_t WS_CSIZE  = 131072;   // float[KCODE]
constexpr size_t WS_COMMIT = 163840;   // float
constexpr size_t WS_CSSUM  = 163844;   // float
constexpr size_t WS_XNORM  = 196608;   // float[NROW]
constexpr size_t WS_ENORM  = 262144;   // float[KCODE]
constexpr size_t WS_ESUM   = 327680;   // float[KCODE*DIM]
constexpr size_t WS_NEEDED = WS_ESUM + (size_t)KCODE * DIM * 4;   // 17,104,896
// pre-split bf16 hi/lo planes (row-major [N][512] u16)
constexpr size_t WS_FH = WS_NEEDED;
constexpr size_t WS_FL = WS_FH + (size_t)NROW * DIM * 2;
constexpr size_t WS_EH = WS_FL + (size_t)NROW * DIM * 2;
constexpr size_t WS_EL = WS_EH + (size_t)KCODE * DIM * 2;
constexpr size_t WS_BIG = WS_EL + (size_t)KCODE * DIM * 2;         // ~67.4 MB

// ---------------- kernel 1: row sum-of-squares, numpy pairwise order --------
__global__ void rownorm_kernel(const float* __restrict__ src, float* __restrict__ dst) {
    #pragma clang fp contract(off)
    __shared__ float s[4][DIM];
    __shared__ float rr[4][32];
    const int wave = threadIdx.x >> 6, lane = threadIdx.x & 63;
    const int row = blockIdx.x * 4 + wave;
    const float4* p = (const float4*)(src + (size_t)row * DIM);
    float4 v0 = p[lane];
    float4 v1 = p[lane + 64];
    *(float4*)&s[wave][lane * 4] = v0;
    *(float4*)&s[wave][(lane + 64) * 4] = v1;
    __syncthreads();
    if (lane < 32) {
        const int b = lane >> 3, j = lane & 7;
        const float* q = &s[wave][b * 128 + j];
        float x = q[0];
        float r = x * x;
        for (int t = 1; t < 16; ++t) {
            float y = q[8 * t];
            float py = y * y;
            r = r + py;
        }
        rr[wave][lane] = r;
    }
    __syncthreads();
    if (lane == 0) {
        const float* R = rr[wave];
        float B0 = ((R[0] + R[1]) + (R[2] + R[3])) + ((R[4] + R[5]) + (R[6] + R[7]));
        float B1 = ((R[8] + R[9]) + (R[10] + R[11])) + ((R[12] + R[13]) + (R[14] + R[15]));
        float B2 = ((R[16] + R[17]) + (R[18] + R[19])) + ((R[20] + R[21]) + (R[22] + R[23]));
        float B3 = ((R[24] + R[25]) + (R[26] + R[27])) + ((R[28] + R[29]) + (R[30] + R[31]));
        dst[row] = (B0 + B1) + (B2 + B3);
    }
}

// ---------------- helpers ---------------------------------------------------
typedef short bf16x8 __attribute__((ext_vector_type(8)));
typedef float f32x16 __attribute__((ext_vector_type(16)));

__device__ __forceinline__ bf16x8 frag_of(int4 t) {
    return __builtin_bit_cast(bf16x8, t);
}

// fp32 -> bf16 round-to-nearest-even (non-NaN inputs), as u32 in low 16 bits
__device__ __forceinline__ u32 bf16rne(float x) {
    u32 u = __float_as_uint(x);
    return (u + 0x7fffu + ((u >> 16) & 1u)) >> 16;
}

// fp32x4 -> bf16 hi (RNE) + bf16 lo (RNE of residual); packed pairs
__device__ __forceinline__ void split4(float4 v, u32& hp0, u32& hp1, u32& lp0, u32& lp1) {
    u32 h0 = bf16rne(v.x), h1 = bf16rne(v.y), h2 = bf16rne(v.z), h3 = bf16rne(v.w);
    hp0 = h0 | (h1 << 16);
    hp1 = h2 | (h3 << 16);
    float r0 = v.x - __uint_as_float(h0 << 16);
    float r1 = v.y - __uint_as_float(h1 << 16);
    float r2 = v.z - __uint_as_float(h2 << 16);
    float r3 = v.w - __uint_as_float(h3 << 16);
    lp0 = bf16rne(r0) | (bf16rne(r1) << 16);
    lp1 = bf16rne(r2) | (bf16rne(r3) << 16);
}

__device__ __forceinline__ u64 packkey(float v, int code) {
    u32 vb = __float_as_uint(v);
    vb = (vb & 0x80000000u) ? ~vb : (vb | 0x80000000u);
    return ((u64)vb << 32) | (u32)code;
}

// async global -> LDS, 16 B per lane; LDS dest = wave-uniform base + lane*16
typedef __attribute__((address_space(1))) const void* gas_ptr;
typedef __attribute__((address_space(3))) void*       las_ptr;
__device__ __forceinline__ void gload16(const void* g, void* l) {
    __builtin_amdgcn_global_load_lds((gas_ptr)(unsigned long long)g,
                                     (las_ptr)(unsigned)(unsigned long long)l,
                                     16, 0, 0);
}

// ---------------- kernel 1b: pre-split fp32 -> bf16 hi/lo -------------------
__global__ void split_kernel(const float* __restrict__ src,
                             u16* __restrict__ hi, u16* __restrict__ lo) {
    const size_t i = (size_t)blockIdx.x * 256 + threadIdx.x;   // 8 floats per thread
    const float4* p = (const float4*)src;
    float4 a = p[i * 2], b = p[i * 2 + 1];
    u32 ah0, ah1, al0, al1, bh0, bh1, bl0, bl1;
    split4(a, ah0, ah1, al0, al1);
    split4(b, bh0, bh1, bl0, bl1);
    ((uint4*)hi)[i] = make_uint4(ah0, ah1, bh0, bh1);
    ((uint4*)lo)[i] = make_uint4(al0, al1, bl0, bl1);
}

// ---------------- kernel 2: argmin via pre-split bf16 MFMA ------------------
// LDS fragment-major: slot i (16B) <-> r=i>>8, rb=(i>>7)&1, k8=(i>>5)&3, c5=i&31
// row_local = r*64 + rb*32 + c5, global int4 idx = row*64 + kt*4 + k8.
// Single-buffer serial structure (R4-proven); occupancy raised to 4 blocks/CU
// via waves_per_eu(4,4) (33 KB LDS, ~88 VGPR <= 128 budget -> no spill).
// Inter-block overlap (4 independent blocks/CU) hides the per-tile drain.
__attribute__((amdgpu_waves_per_eu(4, 4)))
__launch_bounds__(256)
__global__ void argmin_ps_kernel(const u16* __restrict__ fH, const u16* __restrict__ fL,
                                 const u16* __restrict__ eH, const u16* __restrict__ eL,
                                 const float* __restrict__ xnorm,
                                 const float* __restrict__ enorm,
                                 u64* __restrict__ keys) {
    __shared__ int4 sAh[512], sAl[512], sBh[512], sBl[512];   // 4 x 8 KB
    __shared__ float sXn[BM], sEn[BN];

    const int tid = threadIdx.x;
    // XCD-bijective swizzle: 8192 % 8 == 0; cp varies fastest inside an XCD
    const int swz = ((int)blockIdx.x & 7) * 1024 + ((int)blockIdx.x >> 3);
    const int cp = swz & 63;
    const int rp = swz >> 6;
    const int row0 = rp * BM;
    const int code0 = cp * BN;

    if (tid < BM) sXn[tid] = xnorm[row0 + tid];
    else          sEn[tid - BM] = enorm[code0 + (tid - BM)];

    const int lane = tid & 63;
    const int wv = tid >> 6;
    const int wr = wv & 1, wc = wv >> 1;          // 2x2 waves over 64x64 sub-tiles
    const int c5 = lane & 31, hgrp = lane >> 5;

    const int4* fH4 = (const int4*)fH;
    const int4* fL4 = (const int4*)fL;
    const int4* eH4 = (const int4*)eH;
    const int4* eL4 = (const int4*)eL;

    // per-lane global offsets (int4 units) for the 2 staged slot-groups
    size_t goA[2], goB[2];
    int gb[2];
    #pragma unroll
    for (int h = 0; h < 2; ++h) {
        const int g = h * 4 + wv;                 // slot-group 0..7
        const int i = g * 64 + lane;
        const int r = i >> 8, rb = (i >> 7) & 1, k8 = (i >> 5) & 3, c5i = i & 31;
        const int rl = r * 64 + rb * 32 + c5i;
        goA[h] = (size_t)(row0 + rl) * 64 + k8;
        goB[h] = (size_t)(code0 + rl) * 64 + k8;
        gb[h] = g * 64;
    }

    f32x16 acc[2][2] = {};

    #pragma unroll 1
    for (int kt = 0; kt < DIM / BK; ++kt) {
        __syncthreads();                          // prior tile fully consumed
        #pragma unroll
        for (int h = 0; h < 2; ++h) {
            gload16(fH4 + goA[h] + kt * 4, (void*)&sAh[gb[h]]);
            gload16(fL4 + goA[h] + kt * 4, (void*)&sAl[gb[h]]);
            gload16(eH4 + goB[h] + kt * 4, (void*)&sBh[gb[h]]);
            gload16(eL4 + goB[h] + kt * 4, (void*)&sBl[gb[h]]);
        }
        asm volatile("s_waitcnt vmcnt(0)" ::: "memory");
        __syncthreads();
        // MFMA: 3-pass split-bf16 (xh*eh + xh*el + xl*eh)
        #pragma unroll
        for (int s = 0; s < 2; ++s) {
            const int k8 = s * 2 + hgrp;
            bf16x8 ah[2], al[2], bh[2], bl[2];
            #pragma unroll
            for (int i = 0; i < 2; ++i) {
                ah[i] = frag_of(sAh[((2 * wr + i) * 4 + k8) * 32 + c5]);
                al[i] = frag_of(sAl[((2 * wr + i) * 4 + k8) * 32 + c5]);
                bh[i] = frag_of(sBh[((2 * wc + i) * 4 + k8) * 32 + c5]);
                bl[i] = frag_of(sBl[((2 * wc + i) * 4 + k8) * 32 + c5]);
            }
            #pragma unroll
            for (int i = 0; i < 2; ++i) {
                #pragma unroll
                for (int j = 0; j < 2; ++j) {
                    acc[i][j] = __builtin_amdgcn_mfma_f32_32x32x16_bf16(ah[i], bh[j], acc[i][j], 0, 0, 0);
                    acc[i][j] = __builtin_amdgcn_mfma_f32_32x32x16_bf16(ah[i], bl[j], acc[i][j], 0, 0, 0);
                    acc[i][j] = __builtin_amdgcn_mfma_f32_32x32x16_bf16(al[i], bh[j], acc[i][j], 0, 0, 0);
                }
            }
        }
    }

    // epilogue: d2 = (xn - 2*dot) + en, per-row argmin, atomicMin key protocol
    #pragma unroll
    for (int i = 0; i < 2; ++i) {
        #pragma unroll
        for (int r = 0; r < 16; ++r) {
            const int rowt = 64 * wr + 32 * i + (r & 3) + 8 * (r >> 2) + 4 * hgrp;
            const float xv = sXn[rowt];
            const int ct0 = 64 * wc + c5;
            float v0 = fmaf(-2.0f, acc[i][0][r], xv) + sEn[ct0];
            float v1 = fmaf(-2.0f, acc[i][1][r], xv) + sEn[ct0 + 32];
            u64 ka = packkey(v0, code0 + ct0);
            u64 kb = packkey(v1, code0 + ct0 + 32);
            u64 key = (kb < ka) ? kb : ka;
            #pragma unroll
            for (int m = 1; m < 32; m <<= 1) {
                u64 o = __shfl_xor(key, m, 64);
                if (o < key) key = o;
            }
            if (c5 == 0) atomicMin(&keys[row0 + rowt], key);
        }
    }
}

// ---------------- kernel 2-fallback: in-loop-convert argmin (round-2) -------
__launch_bounds__(256, 3)
__global__ void argmin_conv_kernel(const float* __restrict__ feat,
                                   const float* __restrict__ emb,
                                   const float* __restrict__ xnorm,
                                   const float* __restrict__ enorm,
                                   u64* __restrict__ keys) {
    __shared__ u16 sAh[BM][LSTR], sAl[BM][LSTR], sBh[BN][LSTR], sBl[BN][LSTR];
    __shared__ float sXn[BM], sEn[BN];

    const int tid = threadIdx.x;
    const int swz = ((int)blockIdx.x & 7) * 1024 + ((int)blockIdx.x >> 3);
    const int cp = swz & 63;
    const int rp = swz >> 6;
    const int row0 = rp * BM;
    const int code0 = cp * BN;

    if (tid < BM) sXn[tid] = xnorm[row0 + tid];
    else          sEn[tid - BM] = enorm[code0 + (tid - BM)];

    const int srow = tid >> 3;
    const int scol = (tid & 7) * 4;
    const float* aBase = feat + (size_t)row0 * DIM;
    const float* bBase = emb + (size_t)code0 * DIM;

    float4 pa[4], pb[4];
    #pragma unroll
    for (int l = 0; l < 4; ++l) {
        pa[l] = *(const float4*)&aBase[(size_t)(srow + 32 * l) * DIM + scol];
        pb[l] = *(const float4*)&bBase[(size_t)(srow + 32 * l) * DIM + scol];
    }

    const int lane = tid & 63;
    const int wv = tid >> 6;
    const int wr = wv & 1, wc = wv >> 1;
    const int c5 = lane & 31, hgrp = lane >> 5;

    f32x16 acc[2][2] = {};

    #pragma unroll 1
    for (int kt = 0; kt < DIM / BK; ++kt) {
        __syncthreads();
        #pragma unroll
        for (int l = 0; l < 4; ++l) {
            u32 h0, h1, q0, q1;
            split4(pa[l], h0, h1, q0, q1);
            *(uint2*)&sAh[srow + 32 * l][scol] = make_uint2(h0, h1);
            *(uint2*)&sAl[srow + 32 * l][scol] = make_uint2(q0, q1);
            split4(pb[l], h0, h1, q0, q1);
            *(uint2*)&sBh[srow + 32 * l][scol] = make_uint2(h0, h1);
            *(uint2*)&sBl[srow + 32 * l][scol] = make_uint2(q0, q1);
        }
        __syncthreads();
        if (kt + 1 < DIM / BK) {
            const int k0 = (kt + 1) * BK;
            #pragma unroll
            for (int l = 0; l < 4; ++l) {
                pa[l] = *(const float4*)&aBase[(size_t)(srow + 32 * l) * DIM + k0 + scol];
                pb[l] = *(const float4*)&bBase[(size_t)(srow + 32 * l) * DIM + k0 + scol];
            }
        }
        #pragma unroll
        for (int s = 0; s < 2; ++s) {
            const int kk = s * 16 + hgrp * 8;
            bf16x8 ah[2], al[2], bh[2], bl[2];
            #pragma unroll
            for (int i = 0; i < 2; ++i) {
                uint2 a0 = *(const uint2*)&sAh[64 * wr + 32 * i + c5][kk];
                uint2 a1 = *(const uint2*)&sAh[64 * wr + 32 * i + c5][kk + 4];
                ah[i] = frag_of(make_int4(a0.x, a0.y, a1.x, a1.y));
                uint2 c0 = *(const uint2*)&sAl[64 * wr + 32 * i + c5][kk];
                uint2 c1 = *(const uint2*)&sAl[64 * wr + 32 * i + c5][kk + 4];
                al[i] = frag_of(make_int4(c0.x, c0.y, c1.x, c1.y));
                uint2 b0 = *(const uint2*)&sBh[64 * wc + 32 * i + c5][kk];
                uint2 b1 = *(const uint2*)&sBh[64 * wc + 32 * i + c5][kk + 4];
                bh[i] = frag_of(make_int4(b0.x, b0.y, b1.x, b1.y));
                uint2 d0 = *(const uint2*)&sBl[64 * wc + 32 * i + c5][kk];
                uint2 d1 = *(const uint2*)&sBl[64 * wc + 32 * i + c5][kk + 4];
                bl[i] = frag_of(make_int4(d0.x, d0.y, d1.x, d1.y));
            }
            #pragma unroll
            for (int i = 0; i < 2; ++i) {
                #pragma unroll
                for (int j = 0; j < 2; ++j) {
                    acc[i][j] = __builtin_amdgcn_mfma_f32_32x32x16_bf16(ah[i], bh[j], acc[i][j], 0, 0, 0);
                    acc[i][j] = __builtin_amdgcn_mfma_f32_32x32x16_bf16(ah[i], bl[j], acc[i][j], 0, 0, 0);
                    acc[i][j] = __builtin_amdgcn_mfma_f32_32x32x16_bf16(al[i], bh[j], acc[i][j], 0, 0, 0);
                }
            }
        }
    }

    #pragma unroll
    for (int i = 0; i < 2; ++i) {
        #pragma unroll
        for (int r = 0; r < 16; ++r) {
            const int rowt = 64 * wr + 32 * i + (r & 3) + 8 * (r >> 2) + 4 * hgrp;
            const float xv = sXn[rowt];
            const int ct0 = 64 * wc + c5;
            float v0 = fmaf(-2.0f, acc[i][0][r], xv) + sEn[ct0];
            float v1 = fmaf(-2.0f, acc[i][1][r], xv) + sEn[ct0 + 32];
            u64 ka = packkey(v0, code0 + ct0);
            u64 kb = packkey(v1, code0 + ct0 + 32);
            u64 key = (kb < ka) ? kb : ka;
            #pragma unroll
            for (int m = 1; m < 32; m <<= 1) {
                u64 o = __shfl_xor(key, m, 64);
                if (o < key) key = o;
            }
            if (c5 == 0) atomicMin(&keys[row0 + rowt], key);
        }
    }
}

// ---------------- kernel 3: gather + commitment + scatter-add ---------------
__global__ void gather_kernel(const float* __restrict__ feat,
                              const float* __restrict__ emb,
                              const unsigned long long* __restrict__ keys,
                              float* __restrict__ qout,
                              float* __restrict__ targets,
                              float* __restrict__ esum,
                              float* __restrict__ csize,
                              float* __restrict__ commit) {
    const int row = blockIdx.x;
    const int code = (int)(keys[row] & 0x7fffffffu);
    const int d = threadIdx.x * 2;
    float2 f = *(const float2*)&feat[(size_t)row * DIM + d];
    float2 q = *(const float2*)&emb[(size_t)code * DIM + d];
    float2 qst;
    qst.x = f.x + (q.x - f.x);
    qst.y = f.y + (q.y - f.y);
    *(float2*)&qout[(size_t)row * DIM + d] = qst;
    float dx = f.x - qst.x, dy = f.y - qst.y;
    float local = dx * dx + dy * dy;
    #pragma unroll
    for (int off = 32; off; off >>= 1) local += __shfl_down(local, off, 64);
    __shared__ float wsum[4];
    int lane = threadIdx.x & 63, wv = threadIdx.x >> 6;
    if (lane == 0) wsum[wv] = local;
    __syncthreads();
    if (threadIdx.x == 0) {
        atomicAdd(commit, wsum[0] + wsum[1] + wsum[2] + wsum[3]);
        atomicAdd(&csize[code], 1.0f);
        targets[row] = (float)code;
    }
    atomicAdd(&esum[(size_t)code * DIM + d], f.x);
    atomicAdd(&esum[(size_t)code * DIM + d + 1], f.y);
}

// ---------------- kernel 4: new_cs + sum(new_cs) + loss ---------------------
__global__ void newcs_kernel(const float* __restrict__ ema_cs,
                             const float* __restrict__ csize,
                             float* __restrict__ out_cs,
                             float* __restrict__ cs_sum,
                             const float* __restrict__ commit,
                             float* __restrict__ out_loss) {
    int i = blockIdx.x * 256 + threadIdx.x;
    float v = 0.99f * ema_cs[i] + 0.01f * csize[i];
    out_cs[i] = v;
    float s = v;
    #pragma unroll
    for (int off = 32; off; off >>= 1) s += __shfl_down(s, off, 64);
    __shared__ float wsum[4];
    int lane = threadIdx.x & 63, wv = threadIdx.x >> 6;
    if (lane == 0) wsum[wv] = s;
    __syncthreads();
    if (threadIdx.x == 0)
        atomicAdd(cs_sum, wsum[0] + wsum[1] + wsum[2] + wsum[3]);
    if (blockIdx.x == 0 && threadIdx.x == 0)
        out_loss[0] = 0.25f * commit[0] / 8388608.0f;
}

// ---------------- kernel 5: new_w + new_embeddings --------------------------
__global__ void final_kernel(const float* __restrict__ ema_w,
                             const float* __restrict__ esum,
                             const float* __restrict__ new_cs,
                             const float* __restrict__ cs_sum,
                             float* __restrict__ out_w,
                             float* __restrict__ out_emb) {
    size_t i4 = ((size_t)blockIdx.x * 256 + threadIdx.x) * 4;
    int k = (int)(i4 >> 9);
    float S = cs_sum[0] + (float)KCODE * 1e-5f;
    float4 es = *(const float4*)&esum[i4];
    float4 ew = *(const float4*)&ema_w[i4];
    float w0 = 0.99f * ew.x + 0.01f * es.x;
    float w1 = 0.99f * ew.y + 0.01f * es.y;
    float w2 = 0.99f * ew.z + 0.01f * es.z;
    float w3 = 0.99f * ew.w + 0.01f * es.w;
    out_w[i4 + 0] = w0; out_w[i4 + 1] = w1; out_w[i4 + 2] = w2; out_w[i4 + 3] = w3;
    float scale = S / (new_cs[k] + 1e-5f);
    out_emb[i4 + 0] = w0 * scale; out_emb[i4 + 1] = w1 * scale;
    out_emb[i4 + 2] = w2 * scale; out_emb[i4 + 3] = w3 * scale;
}

// ---------------------------------------------------------------------------
extern "C" void kernel_launch(void* const* d_in, const int* in_sizes, int n_in,
                              void* d_out, int out_size, void* d_ws, size_t ws_size,
                              hipStream_t stream) {
    const float* feat   = (const float*)d_in[0];
    const float* emb    = (const float*)d_in[1];
    const float* ema_cs = (const float*)d_in[2];
    const float* ema_w  = (const float*)d_in[3];
    float* out = (float*)d_out;
    char* ws = (char*)d_ws;
    if (ws_size < WS_NEEDED) return;

    u64* keys     = (u64*)(ws + WS_KEYS);
    float* csize  = (float*)(ws + WS_CSIZE);
    float* commit = (float*)(ws + WS_COMMIT);
    float* cssum  = (float*)(ws + WS_CSSUM);
    float* xnorm  = (float*)(ws + WS_XNORM);
    float* enorm  = (float*)(ws + WS_ENORM);
    float* esum   = (float*)(ws + WS_ESUM);

    (void)hipMemsetAsync(ws + WS_KEYS, 0xFF, (size_t)NROW * 8, stream);
    (void)hipMemsetAsync(ws + WS_CSIZE, 0, WS_CSSUM + 4 - WS_CSIZE, stream);
    (void)hipMemsetAsync(ws + WS_ESUM, 0, (size_t)KCODE * DIM * 4, stream);

    rownorm_kernel<<<NROW / 4, 256, 0, stream>>>(feat, xnorm);
    rownorm_kernel<<<KCODE / 4, 256, 0, stream>>>(emb, enorm);

    if (ws_size >= WS_BIG) {
        u16* fH = (u16*)(ws + WS_FH);
        u16* fL = (u16*)(ws + WS_FL);
        u16* eH = (u16*)(ws + WS_EH);
        u16* eL = (u16*)(ws + WS_EL);
        split_kernel<<<(NROW * DIM) / (256 * 8), 256, 0, stream>>>(feat, fH, fL);
        split_kernel<<<(KCODE * DIM) / (256 * 8), 256, 0, stream>>>(emb, eH, eL);
        argmin_ps_kernel<<<(NROW / BM) * (KCODE / BN), 256, 0, stream>>>(fH, fL, eH, eL,
                                                                         xnorm, enorm, keys);
    } else {
        argmin_conv_kernel<<<(NROW / BM) * (KCODE / BN), 256, 0, stream>>>(feat, emb,
                                                                           xnorm, enorm, keys);
    }

    gather_kernel<<<NROW, 256, 0, stream>>>(feat, emb, keys, out + Q_OFF, out + T_OFF,
                                            esum, csize, commit);
    newcs_kernel<<<KCODE / 256, 256, 0, stream>>>(ema_cs, csize, out + C_OFF, cssum, commit, out + L_OFF);
    final_kernel<<<KCODE * DIM / 1024, 256, 0, stream>>>(ema_w, esum, out + C_OFF, cssum,
                                                         out + W_OFF, out + E_OFF);
}